// Round 15
// baseline (44.651 us; speedup 1.0000x reference)
//
#include <hip/hip_runtime.h>

// Problem geometry (fixed by the reference setup_inputs()):
//   k, v : (B=4, S=4096, F=1024) float32
//   out  : concat(qk, qv) flat, float32
constexpr int B = 4;
constexpr int S = 4096;
constexpr int F = 1024;

// NUMERICS (rounds 1-14): the golden is the XLA-compiled jax reference with
// BOTH algebraic-simplifier rewrites:
//   (1) scale = amax / 7.0        ==>  amax * fl32(1/7)        [R14 proved:
//       switching to this made Output 0 (k) PASS after 13 failures]
//   (2) q = x / broadcast(safe)   ==>  x * broadcast(fl32(1/safe))
//       [XLA hoists the divide to the small (1,S,1) shape and multiplies on
//       the (4,S,1024) shape]. R14 used faithful f32 division and missed
//       exactly ONE element (C, in v, 0.53125 = one quant step): the
//       1-ulp double-rounding of fl32(1/safe) flips rare near-boundary
//       elements — zero landed in k, one in v. R10 (inv of the DIVISION
//       scale s_d) failed because fl32(1/s_d) != fl32(1/s_m) at the marker
//       tokens.
// Pipeline: all f32. scale = m*R7; safe = scale>0?scale:1; inv = 1/safe;
// q = rint(x*inv) (half-even = jnp.round); clip [-8,7]; out = q*safe;
// passthrough where scale<=0.
__global__ __launch_bounds__(256) void kvquant_int4_per_token(
        const float* __restrict__ k,
        const float* __restrict__ v,
        float* __restrict__ out) {
    const int bid = blockIdx.x;           // [0, 2*S)
    const int tensor = (bid >= S) ? 1 : 0;
    const int t = tensor ? (bid - S) : bid;
    const float* __restrict__ src = tensor ? v : k;
    float* __restrict__ dst = out + (size_t)tensor * ((size_t)B * S * F);

    const int tid = threadIdx.x;
    const size_t base = (size_t)t * F + (size_t)tid * 4;

    // Load: one float4 per batch index (coalesced, 16 B/lane).
    float4 vals[B];
#pragma unroll
    for (int b = 0; b < B; ++b)
        vals[b] = *reinterpret_cast<const float4*>(src + (size_t)b * ((size_t)S * F) + base);

    // Per-thread absmax over the 16 held values (exact in fp32).
    float m = 0.0f;
#pragma unroll
    for (int b = 0; b < B; ++b) {
        m = fmaxf(m, fabsf(vals[b].x));
        m = fmaxf(m, fabsf(vals[b].y));
        m = fmaxf(m, fabsf(vals[b].z));
        m = fmaxf(m, fabsf(vals[b].w));
    }

    // Wave-64 butterfly max-reduce.
#pragma unroll
    for (int off = 32; off > 0; off >>= 1)
        m = fmaxf(m, __shfl_xor(m, off, 64));

    // Cross-wave (4 waves) reduce via LDS.
    __shared__ float smax[4];
    const int wave = tid >> 6;
    if ((tid & 63) == 0) smax[wave] = m;
    __syncthreads();
    m = fmaxf(fmaxf(smax[0], smax[1]), fmaxf(smax[2], smax[3]));

    // XLA rewrite (1): scale = m * fl32(1/7)  (single f32 multiply).
    const float R7    = 1.0f / 7.0f;       // constant-folded fl32(1/7)
    const float scale = m * R7;
    const bool  qz    = (scale > 0.0f);
    const float safe  = qz ? scale : 1.0f;

    // XLA rewrite (2): per-token reciprocal, computed ONCE (IEEE f32 div),
    // then elementwise multiply — the fl32(1/safe) double-rounding is part
    // of the golden's semantics.
    const float inv = 1.0f / safe;

    // q = rintf(x * inv) (half-even), clip [-8,7], dequant by safe.
#pragma unroll
    for (int b = 0; b < B; ++b) {
        float4 o;
        const float* pi = &vals[b].x;
        float* po = &o.x;
#pragma unroll
        for (int j = 0; j < 4; ++j) {
            const float x = pi[j];
            float q = rintf(x * inv);
            q = fminf(fmaxf(q, -8.0f), 7.0f);
            po[j] = qz ? (q * safe) : x;
        }
        *reinterpret_cast<float4*>(dst + (size_t)b * ((size_t)S * F) + base) = o;
    }
}

extern "C" void kernel_launch(void* const* d_in, const int* in_sizes, int n_in,
                              void* d_out, int out_size, void* d_ws, size_t ws_size,
                              hipStream_t stream) {
    const float* k = (const float*)d_in[0];
    const float* v = (const float*)d_in[1];
    float* out = (float*)d_out;

    // 2 tensors * S timesteps blocks, 256 threads each.
    kvquant_int4_per_token<<<2 * S, 256, 0, stream>>>(k, v, out);
}